// Round 11
// baseline (111.394 us; speedup 1.0000x reference)
//
#include <hip/hip_runtime.h>
#include <cstddef>

// Problem constants (match reference)
#define T_STEPS 32
#define B_SZ    512
#define S_SZ    64
#define F_INPUT 128
#define H1      256
#define H2      256
#define H3      128

typedef _Float16 half_t;
typedef __attribute__((ext_vector_type(8))) _Float16 half8;
typedef __attribute__((ext_vector_type(4))) float   float4v;

// ---------------------------------------------------------------------------
// Kernel 0: pre-split + SWIZZLE weights into MFMA-fragment order (unchanged
// from R6..R10 — verified exact).
//   hi = f16(w) (flushed if f16-denormal), lo = f16((w - hi) * 2^12)
// Tile (n_tile, k_chunk) = 1024 halfs: [0,512) hi, [512,1024) lo, element
// (lr=n&15, quad=kin>>3, j=kin&7) at (quad*16+lr)*8 + j.
// Wave B-frag load = base + lane*8 -> 1 KB fully coalesced, L2-resident.
// ---------------------------------------------------------------------------
__device__ inline void split_store_sw(float w, half_t* out, int n, int k, int kchunks) {
    half_t hi = (half_t)w;
    float hif = (float)hi;
    if (fabsf(hif) < 6.103515625e-05f) { hi = (half_t)0.0f; hif = 0.0f; }
    half_t lo = (half_t)((w - hif) * 4096.0f);
    int n_tile = n >> 4, lr = n & 15;
    int k_chunk = k >> 5, kin = k & 31, quad = kin >> 3, j = kin & 7;
    size_t base = (size_t)(n_tile * kchunks + k_chunk) * 1024;
    size_t off  = base + (size_t)((quad << 4) + lr) * 8 + j;
    out[off]       = hi;
    out[off + 512] = lo;
}

__global__ __launch_bounds__(256)
void prep_w_kernel(const float* __restrict__ W1, const float* __restrict__ W2,
                   const float* __restrict__ W3,
                   half_t* __restrict__ ws1, half_t* __restrict__ ws2,
                   half_t* __restrict__ ws3) {
    int e = blockIdx.x * blockDim.x + threadIdx.x;   // 0..131071
    if (e < H1 * F_INPUT) {                          // 256 x 128, kchunks=4
        split_store_sw(W1[e], ws1, e / F_INPUT, e % F_INPUT, F_INPUT / 32);
    } else if (e < H1 * F_INPUT + H2 * H1) {         // 256 x 256, kchunks=8
        int i = e - H1 * F_INPUT;
        split_store_sw(W2[i], ws2, i / H1, i % H1, H1 / 32);
    } else {                                         // 128 x 256, kchunks=8
        int i = e - H1 * F_INPUT - H2 * H1;
        split_store_sw(W3[i], ws3, i / H2, i % H2, H2 / 32);
    }
}

// ---------------------------------------------------------------------------
// Kernel 1: latency encode, one block per batch (R10's register-burst body,
// writing rates to GLOBAL b-major f16 [b*32+t][128]).
// ---------------------------------------------------------------------------
__global__ __launch_bounds__(256)
void encode_kernel(const float* __restrict__ x, half_t* __restrict__ rates) {
    __shared__ float scratch[8192];              // 32 KB: minmax then hist[2][32][128]
    const int tid = threadIdx.x;
    const int b   = blockIdx.x;
    const int f   = tid & 127;
    const int sh  = tid >> 7;                    // s-half: 0 -> s 0..31, 1 -> 32..63
    const float* xp = x + (size_t)b * (S_SZ * F_INPUT) + (size_t)sh * 32 * F_INPUT + f;

    float v[32];                                 // burst loads, all in flight
#pragma unroll
    for (int s = 0; s < 32; ++s) {
        float val = xp[(size_t)s * F_INPUT];
        v[s] = (val < 0.75f) ? 0.0f : val;       // gate at ENC_THR
    }
    float mn = 1e30f, mx = -1e30f;
#pragma unroll
    for (int s = 0; s < 32; ++s) {
        mn = fminf(mn, v[s]);
        mx = fmaxf(mx, v[s]);
    }
    scratch[sh * 128 + f]       = mn;
    scratch[256 + sh * 128 + f] = mx;
    __syncthreads();
    // exact: min(min half0, min half1) == min(all); same for max
    float fmn = fminf(scratch[f], scratch[128 + f]);
    float fmx = fmaxf(scratch[256 + f], scratch[384 + f]);
    __syncthreads();

#pragma unroll
    for (int t = 0; t < T_STEPS; ++t) scratch[sh * 4096 + t * 128 + f] = 0.0f;
    // no barrier: each thread touches only its own (sh,*,f) cells
    const float denom = fmx - fmn + 1e-8f;
#pragma unroll
    for (int s = 0; s < 32; ++s) {
        float g  = v[s];
        float xn = (g - fmn) / denom;
        float d  = fmaxf(xn, 0.0100001f);        // clip(xn, LAT_THR+EPS)
        float tt = logf(d / (d - 0.01f));        // log latency code
        tt = tt * 31.0f;
        tt = tt / 11.512935464920229f;           // float32(log((thr+eps)/eps))
        float tr = rintf(tt);                    // half-to-even == jnp.round
        tr = fminf(fmaxf(tr, 0.0f), 31.0f);
        scratch[sh * 4096 + (int)tr * 128 + f] += 1.0f;
    }
    __syncthreads();

    // merge halves -> rates (exact k/64) f16, coalesced
#pragma unroll
    for (int i = 0; i < 16; ++i) {
        int idx = tid + i * 256;                 // 0..4095
        int t = idx >> 7, ff = idx & 127;
        float cnt = scratch[t * 128 + ff] + scratch[4096 + t * 128 + ff];
        rates[((size_t)b * T_STEPS + t) * F_INPUT + ff] = (half_t)(cnt * 0.015625f);
    }
}

// ---------------------------------------------------------------------------
// Kernel 2: per-layer fused GEMM + LIF, tiled over (batch, 128-col n-range).
// CHANGED vs R10 mega: independent small blocks instead of one serial
// phase-chain per batch — R10's counters (MfmaUtil 5%, VALUBusy 17%, HBM 4%,
// occ 39%) showed ~75% stall structural to the lock-step chain. Here 4
// blocks/CU sit in different phases and cover each other's latency.
//   C[m][n] = sum_k A[m][k]*(hi + 2^-12 lo)[n][k] + bias[n]
// A: [32 rows of batch b][K] f16 from global -> LDS; W: swizzled, streamed
// from L2 (no LDS, no K-loop barriers); per-accumulator MFMA order identical
// to R6..R10 -> bit-exact. Scan: 128 threads, col h, t=0..31 -> spk/out.
// ---------------------------------------------------------------------------
#define CUR_STRIDE 132                 // floats (128+4)
#define SMEM_AS_MAX 16896              // [32][264] halfs (K=256 case)
#define SMEM_GEMM  (SMEM_AS_MAX + 32 * CUR_STRIDE * 4)   // 33792 B

template<int KCH, int FINAL>
__global__ __launch_bounds__(256)
void gemm_lif(const half_t* __restrict__ A,      // [16384][K] f16, b-major rows
              const half_t* __restrict__ Wsw,
              const float*  __restrict__ bias,
              half_t* __restrict__ spk_next,     // FINAL=0: [16384][Nfull] f16
              float*  __restrict__ out_final,    // FINAL=1: [t*512+b][128] f32
              int Nfull) {
    constexpr int K = KCH * 32;
    constexpr int ASTRIDE = K + 8;               // halfs; +8 pad
    __shared__ __align__(16) char smem[SMEM_GEMM];
    half_t* As   = (half_t*)smem;                // [32][ASTRIDE]
    float*  curT = (float*)(smem + SMEM_AS_MAX); // [32][CUR_STRIDE]

    const int tid  = threadIdx.x;
    const int b    = blockIdx.x;
    const int n0   = blockIdx.y * 128;
    const int wave = tid >> 6;                   // 0..3
    const int lane = tid & 63;
    const int quad = lane >> 4, lr = lane & 15;

    // ---- stage A rows (32 x K halfs), coalesced 16B chunks ----
#pragma unroll
    for (int i = 0; i < KCH / 2; ++i) {
        int idx  = i * 256 + tid;                // 0 .. 4*K-1... (KCH/2)*256
        int row  = idx / (KCH * 4);
        int colh = (idx % (KCH * 4)) * 8;
        *(uint4*)(&As[row * ASTRIDE + colh]) =
            *(const uint4*)(A + ((size_t)b * 32 + row) * K + colh);
    }
    __syncthreads();

    // ---- K-loop: depth-1 W prefetch, no barriers ----
    float4v acc_h[2][2], acc_l[2][2];
#pragma unroll
    for (int mt = 0; mt < 2; ++mt)
#pragma unroll
        for (int nt = 0; nt < 2; ++nt) {
            acc_h[mt][nt] = (float4v){0.0f, 0.0f, 0.0f, 0.0f};
            acc_l[mt][nt] = (float4v){0.0f, 0.0f, 0.0f, 0.0f};
        }
    const int ntile0 = (n0 >> 4) + wave * 2;     // this wave's first n-tile

    half8 wh[2], wl[2];
#pragma unroll
    for (int nt = 0; nt < 2; ++nt) {
        const half_t* p = Wsw + ((size_t)(ntile0 + nt) * KCH) * 1024 + lane * 8;
        wh[nt] = *(const half8*)(p);
        wl[nt] = *(const half8*)(p + 512);
    }
#pragma unroll
    for (int c = 0; c < KCH; ++c) {
        half8 a0 = *(const half8*)(&As[lr * ASTRIDE        + c * 32 + quad * 8]);
        half8 a1 = *(const half8*)(&As[(16 + lr) * ASTRIDE + c * 32 + quad * 8]);
        half8 nwh[2], nwl[2];
        if (c + 1 < KCH) {
#pragma unroll
            for (int nt = 0; nt < 2; ++nt) {
                const half_t* p =
                    Wsw + ((size_t)(ntile0 + nt) * KCH + c + 1) * 1024 + lane * 8;
                nwh[nt] = *(const half8*)(p);
                nwl[nt] = *(const half8*)(p + 512);
            }
        }
#pragma unroll
        for (int nt = 0; nt < 2; ++nt) {
            acc_h[0][nt] = __builtin_amdgcn_mfma_f32_16x16x32_f16(a0, wh[nt], acc_h[0][nt], 0, 0, 0);
            acc_h[1][nt] = __builtin_amdgcn_mfma_f32_16x16x32_f16(a1, wh[nt], acc_h[1][nt], 0, 0, 0);
            acc_l[0][nt] = __builtin_amdgcn_mfma_f32_16x16x32_f16(a0, wl[nt], acc_l[0][nt], 0, 0, 0);
            acc_l[1][nt] = __builtin_amdgcn_mfma_f32_16x16x32_f16(a1, wl[nt], acc_l[1][nt], 0, 0, 0);
        }
#pragma unroll
        for (int nt = 0; nt < 2; ++nt) { wh[nt] = nwh[nt]; wl[nt] = nwl[nt]; }
    }

    // ---- epilogue -> curT (C/D layout: col=lane&15, row=quad*4+reg) ----
#pragma unroll
    for (int nt = 0; nt < 2; ++nt) {
        int col = (wave * 2 + nt) * 16 + lr;     // 0..127 local
        float bj = bias[n0 + col];
#pragma unroll
        for (int mt = 0; mt < 2; ++mt) {
            int rbase = mt * 16 + quad * 4;
#pragma unroll
            for (int r = 0; r < 4; ++r) {
                float v = acc_h[mt][nt][r] + 2.44140625e-04f * acc_l[mt][nt][r];
                curT[(rbase + r) * CUR_STRIDE + col] = v + bj;
            }
        }
    }
    __syncthreads();

    // ---- LIF scan: 128 threads, col h, serial t. fp contract OFF (matches
    // reference mul/add/sub rounding at the threshold) ----
    if (tid < 128) {
#pragma clang fp contract(off)
        const int h = tid;
        float mem = 0.0f;
#pragma unroll
        for (int t = 0; t < T_STEPS; ++t) {
            float c = curT[t * CUR_STRIDE + h];
            float reset = (mem - 1.0f > 0.0f) ? 1.0f : 0.0f;
            float p = 0.9f * mem;
            p = p + c;
            mem = p - reset;
            float s = (mem - 1.0f > 0.0f) ? 1.0f : 0.0f;
            if (FINAL) {
                out_final[((size_t)t * B_SZ + b) * H3 + h] = s;
            } else {
                spk_next[((size_t)b * T_STEPS + t) * Nfull + n0 + h] = (half_t)s;
            }
        }
    }
}

// ---------------------------------------------------------------------------
extern "C" void kernel_launch(void* const* d_in, const int* in_sizes, int n_in,
                              void* d_out, int out_size, void* d_ws, size_t ws_size,
                              hipStream_t stream) {
    const float* x  = (const float*)d_in[0];
    const float* W1 = (const float*)d_in[1];
    const float* b1 = (const float*)d_in[2];
    const float* W2 = (const float*)d_in[3];
    const float* b2 = (const float*)d_in[4];
    const float* W3 = (const float*)d_in[5];
    const float* b3 = (const float*)d_in[6];
    float* out = (float*)d_out;

    char* ws = (char*)d_ws;
    half_t* ws1   = (half_t*)ws;                              // 128 KB swizzled
    half_t* ws2   = (half_t*)(ws + 128 * 1024);               // 256 KB
    half_t* ws3   = (half_t*)(ws + 384 * 1024);               // 128 KB
    half_t* rates = (half_t*)(ws + (size_t) 1 * 1024 * 1024); // 4 MB  [16384][128]
    half_t* spk1  = (half_t*)(ws + (size_t) 5 * 1024 * 1024); // 8 MB  [16384][256]
    half_t* spk2  = (half_t*)(ws + (size_t)13 * 1024 * 1024); // 8 MB  [16384][256]

    // 0. split + swizzle weights
    prep_w_kernel<<<(H1 * F_INPUT + H2 * H1 + H3 * H2) / 256, 256, 0, stream>>>(
        W1, W2, W3, ws1, ws2, ws3);

    // 1. encode: x -> rates f16 b-major
    encode_kernel<<<B_SZ, 256, 0, stream>>>(x, rates);

    // 2. layer 1: K=128 (KCH=4), N=256 -> spk1.   grid (512 batches, 2 n-halves)
    gemm_lif<4, 0><<<dim3(B_SZ, 2), 256, 0, stream>>>(
        rates, ws1, b1, spk1, nullptr, H1);

    // 3. layer 2: K=256 (KCH=8), N=256 -> spk2.
    gemm_lif<8, 0><<<dim3(B_SZ, 2), 256, 0, stream>>>(
        spk1, ws2, b2, spk2, nullptr, H2);

    // 4. layer 3: K=256 (KCH=8), N=128 -> d_out (reference layout [t*B+b][h]).
    gemm_lif<8, 1><<<dim3(B_SZ, 1), 256, 0, stream>>>(
        spk2, ws3, b3, nullptr, out, H3);
}

// Round 12
// 99.394 us; speedup vs baseline: 1.1207x; 1.1207x over previous
//
#include <hip/hip_runtime.h>
#include <cstddef>

// Problem constants (match reference)
#define T_STEPS 32
#define B_SZ    512
#define S_SZ    64
#define F_INPUT 128
#define H1      256
#define H2      256
#define H3      128

typedef _Float16 half_t;
typedef __attribute__((ext_vector_type(8))) _Float16 half8;
typedef __attribute__((ext_vector_type(4))) float   float4v;

// ---------------------------------------------------------------------------
// Kernel 0: pre-split + SWIZZLE weights into MFMA-fragment order (unchanged
// from R6..R11 — verified exact).
//   hi = f16(w) (flushed if f16-denormal), lo = f16((w - hi) * 2^12)
// Tile (n_tile, k_chunk) = 1024 halfs: [0,512) hi, [512,1024) lo, element
// (lr=n&15, quad=kin>>3, j=kin&7) at (quad*16+lr)*8 + j.
// Wave B-frag load = base + lane*8 -> 1 KB fully coalesced, L2-resident.
// ---------------------------------------------------------------------------
__device__ inline void split_store_sw(float w, half_t* out, int n, int k, int kchunks) {
    half_t hi = (half_t)w;
    float hif = (float)hi;
    if (fabsf(hif) < 6.103515625e-05f) { hi = (half_t)0.0f; hif = 0.0f; }
    half_t lo = (half_t)((w - hif) * 4096.0f);
    int n_tile = n >> 4, lr = n & 15;
    int k_chunk = k >> 5, kin = k & 31, quad = kin >> 3, j = kin & 7;
    size_t base = (size_t)(n_tile * kchunks + k_chunk) * 1024;
    size_t off  = base + (size_t)((quad << 4) + lr) * 8 + j;
    out[off]       = hi;
    out[off + 512] = lo;
}

__global__ __launch_bounds__(256)
void prep_w_kernel(const float* __restrict__ W1, const float* __restrict__ W2,
                   const float* __restrict__ W3,
                   half_t* __restrict__ ws1, half_t* __restrict__ ws2,
                   half_t* __restrict__ ws3) {
    int e = blockIdx.x * blockDim.x + threadIdx.x;   // 0..131071
    if (e < H1 * F_INPUT) {                          // 256 x 128, kchunks=4
        split_store_sw(W1[e], ws1, e / F_INPUT, e % F_INPUT, F_INPUT / 32);
    } else if (e < H1 * F_INPUT + H2 * H1) {         // 256 x 256, kchunks=8
        int i = e - H1 * F_INPUT;
        split_store_sw(W2[i], ws2, i / H1, i % H1, H1 / 32);
    } else {                                         // 128 x 256, kchunks=8
        int i = e - H1 * F_INPUT - H2 * H1;
        split_store_sw(W3[i], ws3, i / H2, i % H2, H2 / 32);
    }
}

// ---------------------------------------------------------------------------
// LDS geometry. CHANGED vs R10: TWO batches per block (64 rows = 2 x 32 t).
// Region A (As for layer-1 rates / curT, aliased with a barrier between
// K-loop reads and epilogue writes) + Region B (spk, = As for layers 2/3).
// Pre-layer-1, both regions serve as minmax/hist scratch.
// Rationale: R10 vs R11 showed the shared ~40us kernel cost tracks W L2
// traffic (512 blocks x 512 KB = 262 MB). 64 rows/block halves it to 131 MB
// and doubles MFMA per W byte.
// ---------------------------------------------------------------------------
#define AS_STRIDE  136   // halfs, layer-1 rates rows (K=128 +8 pad)
#define SPK_STRIDE 264   // halfs, spike rows (K=256 +8 pad)
#define CUR_STRIDE 132   // floats, cur rows (N<=256 cols used, +4 pad)
#define SMEM_A     0         // 34816 B: As(17408 used) / curT(33792 used)
#define SMEM_B     34816     // 33792 B: spk (64 x 264 halfs)
#define SMEM_TOTAL 68608     // 67 KB -> 1 block/CU (grid 256 = CU count)

// GEMM phase: C[m][n] = sum_k A[m][k]*(hi + 2^-12 lo)[n][k] + bias[n]
// MT=4 row-tiles (64 rows), NT n-tiles/wave, depth-1 W prefetch, no K-loop
// barriers. Per-accumulator operand sequence identical to R6..R11 -> bit-exact.
// __syncthreads before the epilogue: curT may alias Als (layer 1).
template<int KCHUNKS, int NT, int ASTRIDE>
__device__ __forceinline__ void gemm_phase(const half_t* __restrict__ Wsw,
                                           const float*  __restrict__ bias,
                                           const half_t* __restrict__ Als,
                                           float* __restrict__ curT,
                                           int wave, int lane) {
    const int quad = lane >> 4, lr = lane & 15;
    float4v acc_h[4][NT], acc_l[4][NT];
#pragma unroll
    for (int mt = 0; mt < 4; ++mt)
#pragma unroll
        for (int nt = 0; nt < NT; ++nt) {
            acc_h[mt][nt] = (float4v){0.0f, 0.0f, 0.0f, 0.0f};
            acc_l[mt][nt] = (float4v){0.0f, 0.0f, 0.0f, 0.0f};
        }

    half8 wh[NT], wl[NT];
#pragma unroll
    for (int nt = 0; nt < NT; ++nt) {
        const half_t* p = Wsw + ((size_t)(wave * NT + nt) * KCHUNKS) * 1024 + lane * 8;
        wh[nt] = *(const half8*)(p);
        wl[nt] = *(const half8*)(p + 512);
    }

#pragma unroll
    for (int c = 0; c < KCHUNKS; ++c) {
        half8 a[4];
#pragma unroll
        for (int mt = 0; mt < 4; ++mt)
            a[mt] = *(const half8*)(Als + (mt * 16 + lr) * ASTRIDE + c * 32 + quad * 8);
        half8 nwh[NT], nwl[NT];
        if (c + 1 < KCHUNKS) {
#pragma unroll
            for (int nt = 0; nt < NT; ++nt) {
                const half_t* p =
                    Wsw + ((size_t)(wave * NT + nt) * KCHUNKS + c + 1) * 1024 + lane * 8;
                nwh[nt] = *(const half8*)(p);
                nwl[nt] = *(const half8*)(p + 512);
            }
        }
#pragma unroll
        for (int nt = 0; nt < NT; ++nt)
#pragma unroll
            for (int mt = 0; mt < 4; ++mt) {
                acc_h[mt][nt] = __builtin_amdgcn_mfma_f32_16x16x32_f16(a[mt], wh[nt], acc_h[mt][nt], 0, 0, 0);
                acc_l[mt][nt] = __builtin_amdgcn_mfma_f32_16x16x32_f16(a[mt], wl[nt], acc_l[mt][nt], 0, 0, 0);
            }
#pragma unroll
        for (int nt = 0; nt < NT; ++nt) { wh[nt] = nwh[nt]; wl[nt] = nwl[nt]; }
    }

    __syncthreads();   // all waves' Als reads done before curT (may alias) is written

    // epilogue -> curT (C/D layout: col=lane&15, row=quad*4+reg)
#pragma unroll
    for (int nt = 0; nt < NT; ++nt) {
        int col = (wave * NT + nt) * 16 + lr;
        float bj = bias[col];
#pragma unroll
        for (int mt = 0; mt < 4; ++mt) {
            int rbase = mt * 16 + quad * 4;
#pragma unroll
            for (int r = 0; r < 4; ++r) {
                float v = acc_h[mt][nt][r] + 2.44140625e-04f * acc_l[mt][nt][r];
                curT[(rbase + r) * CUR_STRIDE + col] = v + bj;
            }
        }
    }
}

// ---------------------------------------------------------------------------
// Mega kernel: one block = TWO batches (2b, 2b+1), 512 threads (8 waves).
// encode -> L1 -> LIF -> L2 -> LIF -> L3 -> LIF -> out; spikes stay in LDS.
// ---------------------------------------------------------------------------
__global__ __launch_bounds__(512)
void snn_mega_kernel(const float* __restrict__ x,
                     const half_t* __restrict__ ws1, const float* __restrict__ b1,
                     const half_t* __restrict__ ws2, const float* __restrict__ b2,
                     const half_t* __restrict__ ws3, const float* __restrict__ b3,
                     float* __restrict__ out) {
    __shared__ __align__(16) char smem[SMEM_TOTAL];
    half_t* As   = (half_t*)(smem + SMEM_A);     // layer-1 A (rates)
    float*  curT = (float*) (smem + SMEM_A);     // aliased (barrier-protected)
    half_t* spk  = (half_t*)(smem + SMEM_B);     // spikes (A for layers 2/3)
    float*  scratch = (float*)smem;              // pre-L1: minmax then hist

    const int tid  = threadIdx.x;
    const int b0   = blockIdx.x * 2;             // first batch of the pair
    const int wave = tid >> 6;
    const int lane = tid & 63;

    // ================= phase 0: latency encode (both batches) =============
    const int bl = tid >> 8;                     // local batch 0/1
    const int u  = tid & 255;
    const int f  = u & 127;
    const int sh = u >> 7;                       // s-half: 0 -> s 0..31, 1 -> 32..63
    const float* xp = x + (size_t)(b0 + bl) * (S_SZ * F_INPUT)
                        + (size_t)sh * 32 * F_INPUT + f;

    float v[32];                                 // burst loads, all in flight
#pragma unroll
    for (int s = 0; s < 32; ++s) {
        float val = xp[(size_t)s * F_INPUT];
        v[s] = (val < 0.75f) ? 0.0f : val;       // gate at ENC_THR
    }
    float mn = 1e30f, mx = -1e30f;
#pragma unroll
    for (int s = 0; s < 32; ++s) {
        mn = fminf(mn, v[s]);
        mx = fmaxf(mx, v[s]);
    }
    // minmax scratch: [0,1024) floats = 4 KB
    scratch[bl * 256 + sh * 128 + f]        = mn;
    scratch[1024 + bl * 256 + sh * 128 + f] = mx;
    __syncthreads();
    // exact: min(min half0, min half1) == min(all); same for max
    float fmn = fminf(scratch[bl * 256 + f], scratch[bl * 256 + 128 + f]);
    float fmx = fmaxf(scratch[1024 + bl * 256 + f], scratch[1024 + bl * 256 + 128 + f]);
    __syncthreads();

    // hist[bl][sh][t][f] floats at bl*16384 + sh*4096 + t*128 + f (64 KB)
    float* hcol = scratch + bl * 16384 + sh * 4096 + f;
#pragma unroll
    for (int t = 0; t < T_STEPS; ++t) hcol[t * 128] = 0.0f;
    // no barrier: each thread touches only its own (bl,sh,*,f) cells
    const float denom = fmx - fmn + 1e-8f;
#pragma unroll
    for (int s = 0; s < 32; ++s) {
        float g  = v[s];
        float xn = (g - fmn) / denom;
        float d  = fmaxf(xn, 0.0100001f);        // clip(xn, LAT_THR+EPS)
        float tt = logf(d / (d - 0.01f));        // log latency code
        tt = tt * 31.0f;
        tt = tt / 11.512935464920229f;           // float32(log((thr+eps)/eps))
        float tr = rintf(tt);                    // half-to-even == jnp.round
        tr = fminf(fmaxf(tr, 0.0f), 31.0f);
        hcol[(int)tr * 128] += 1.0f;
    }
    __syncthreads();

    // merge sh-halves into registers, then (after barrier) write rates into
    // As — As aliases the hist bytes, so reads must complete first.
    float cnt[16];
#pragma unroll
    for (int i = 0; i < 16; ++i) {
        int idx = tid + i * 512;                 // 0..8191
        int blb = idx >> 12, rem = idx & 4095;
        int t = rem >> 7, ff = rem & 127;
        cnt[i] = scratch[blb * 16384 + t * 128 + ff]
               + scratch[blb * 16384 + 4096 + t * 128 + ff];
    }
    __syncthreads();
#pragma unroll
    for (int i = 0; i < 16; ++i) {
        int idx = tid + i * 512;
        int blb = idx >> 12, rem = idx & 4095;
        int t = rem >> 7, ff = rem & 127;
        As[(blb * 32 + t) * AS_STRIDE + ff] = (half_t)(cnt[i] * 0.015625f);
    }
    __syncthreads();

    // ================= layer 1: GEMM (K=128, N=256) + LIF =================
    gemm_phase<F_INPUT / 32, 2, AS_STRIDE>(ws1, b1, As, curT, wave, lane);
    __syncthreads();
    {
#pragma clang fp contract(off)
        const int sb = tid >> 8;                 // local batch
        const int h  = tid & 255;                // col
        float mem = 0.0f;
#pragma unroll
        for (int t = 0; t < T_STEPS; ++t) {
            float c = curT[(sb * 32 + t) * CUR_STRIDE + h];
            float reset = (mem - 1.0f > 0.0f) ? 1.0f : 0.0f;
            float p = 0.9f * mem;
            p = p + c;
            mem = p - reset;
            spk[(sb * 32 + t) * SPK_STRIDE + h] = (half_t)((mem - 1.0f > 0.0f) ? 1.0f : 0.0f);
        }
    }
    __syncthreads();

    // ================= layer 2: GEMM (K=256, N=256) + LIF =================
    gemm_phase<H1 / 32, 2, SPK_STRIDE>(ws2, b2, spk, curT, wave, lane);
    __syncthreads();
    {
#pragma clang fp contract(off)
        const int sb = tid >> 8;
        const int h  = tid & 255;
        float mem = 0.0f;
#pragma unroll
        for (int t = 0; t < T_STEPS; ++t) {
            float c = curT[(sb * 32 + t) * CUR_STRIDE + h];
            float reset = (mem - 1.0f > 0.0f) ? 1.0f : 0.0f;
            float p = 0.9f * mem;
            p = p + c;
            mem = p - reset;
            spk[(sb * 32 + t) * SPK_STRIDE + h] = (half_t)((mem - 1.0f > 0.0f) ? 1.0f : 0.0f);
        }
    }
    __syncthreads();

    // ================= layer 3: GEMM (K=256, N=128) + LIF -> out ==========
    gemm_phase<H2 / 32, 1, SPK_STRIDE>(ws3, b3, spk, curT, wave, lane);
    __syncthreads();
    if (tid < 256) {
#pragma clang fp contract(off)
        const int sb = tid >> 7;                 // local batch
        const int h  = tid & 127;
        const int bglob = b0 + sb;
        float mem = 0.0f;
#pragma unroll
        for (int t = 0; t < T_STEPS; ++t) {
            float c = curT[(sb * 32 + t) * CUR_STRIDE + h];
            float reset = (mem - 1.0f > 0.0f) ? 1.0f : 0.0f;
            float p = 0.9f * mem;
            p = p + c;
            mem = p - reset;
            // reference output layout: [t*B + b][h], f32
            out[((size_t)t * B_SZ + bglob) * H3 + h] = (mem - 1.0f > 0.0f) ? 1.0f : 0.0f;
        }
    }
}

// ---------------------------------------------------------------------------
extern "C" void kernel_launch(void* const* d_in, const int* in_sizes, int n_in,
                              void* d_out, int out_size, void* d_ws, size_t ws_size,
                              hipStream_t stream) {
    const float* x  = (const float*)d_in[0];
    const float* W1 = (const float*)d_in[1];
    const float* b1 = (const float*)d_in[2];
    const float* W2 = (const float*)d_in[3];
    const float* b2 = (const float*)d_in[4];
    const float* W3 = (const float*)d_in[5];
    const float* b3 = (const float*)d_in[6];
    float* out = (float*)d_out;

    char* ws = (char*)d_ws;
    half_t* ws1 = (half_t*)ws;                          // 128 KB (swizzled hi/lo)
    half_t* ws2 = (half_t*)(ws + 128 * 1024);           // 256 KB
    half_t* ws3 = (half_t*)(ws + 384 * 1024);           // 128 KB

    // 0. split + swizzle weights (one dispatch, all layers)
    prep_w_kernel<<<(H1 * F_INPUT + H2 * H1 + H3 * H2) / 256, 256, 0, stream>>>(
        W1, W2, W3, ws1, ws2, ws3);

    // 1. whole network: one block per batch-PAIR (256 blocks = 1/CU),
    //    8 waves, spikes stay in LDS, W L2 traffic halved vs R10
    snn_mega_kernel<<<B_SZ / 2, 512, 0, stream>>>(x, ws1, b1, ws2, b2, ws3, b3, out);
}

// Round 14
// 97.085 us; speedup vs baseline: 1.1474x; 1.0238x over previous
//
#include <hip/hip_runtime.h>
#include <cstddef>

// Problem constants (match reference)
#define T_STEPS 32
#define B_SZ    512
#define S_SZ    64
#define F_INPUT 128
#define H1      256
#define H2      256
#define H3      128

typedef _Float16 half_t;
typedef __attribute__((ext_vector_type(8))) _Float16 half8;
typedef __attribute__((ext_vector_type(4))) float   float4v;

// ---------------------------------------------------------------------------
// Kernel 0: pre-split + SWIZZLE weights into MFMA-fragment order (unchanged
// from R6..R13 — verified exact).
//   hi = f16(w) (flushed if f16-denormal), lo = f16((w - hi) * 2^12)
// Tile (n_tile, k_chunk) = 1024 halfs: [0,512) hi, [512,1024) lo, element
// (lr=n&15, quad=kin>>3, j=kin&7) at (quad*16+lr)*8 + j.
// ---------------------------------------------------------------------------
__device__ inline void split_store_sw(float w, half_t* out, int n, int k, int kchunks) {
    half_t hi = (half_t)w;
    float hif = (float)hi;
    if (fabsf(hif) < 6.103515625e-05f) { hi = (half_t)0.0f; hif = 0.0f; }
    half_t lo = (half_t)((w - hif) * 4096.0f);
    int n_tile = n >> 4, lr = n & 15;
    int k_chunk = k >> 5, kin = k & 31, quad = kin >> 3, j = kin & 7;
    size_t base = (size_t)(n_tile * kchunks + k_chunk) * 1024;
    size_t off  = base + (size_t)((quad << 4) + lr) * 8 + j;
    out[off]       = hi;
    out[off + 512] = lo;
}

__global__ __launch_bounds__(256)
void prep_w_kernel(const float* __restrict__ W1, const float* __restrict__ W2,
                   const float* __restrict__ W3,
                   half_t* __restrict__ ws1, half_t* __restrict__ ws2,
                   half_t* __restrict__ ws3) {
    int e = blockIdx.x * blockDim.x + threadIdx.x;   // 0..131071
    if (e < H1 * F_INPUT) {                          // 256 x 128, kchunks=4
        split_store_sw(W1[e], ws1, e / F_INPUT, e % F_INPUT, F_INPUT / 32);
    } else if (e < H1 * F_INPUT + H2 * H1) {         // 256 x 256, kchunks=8
        int i = e - H1 * F_INPUT;
        split_store_sw(W2[i], ws2, i / H1, i % H1, H1 / 32);
    } else {                                         // 128 x 256, kchunks=8
        int i = e - H1 * F_INPUT - H2 * H1;
        split_store_sw(W3[i], ws3, i / H2, i % H2, H2 / 32);
    }
}

// ---------------------------------------------------------------------------
// LDS geometry. R13 FIXED: CUR_STRIDE 132 -> 260. With 256 cols, stride 132
// made row*stride+col NON-INJECTIVE ((r,c) collided with (r+1,c-132) across
// waves -> absmax 1.0). Stride 260 >= 256+pad is injective; each wave's scan
// cols are then written ONLY by that wave, so the no-barrier same-wave scan
// is race-free (per-wave DS ops in-order). [R12 shipped the same latent
// collision and "passed" — treat that pass as luck, not evidence.]
// ---------------------------------------------------------------------------
#define AS_STRIDE  136   // halfs, rates rows (K=128 +8 pad)
#define SPK_STRIDE 264   // halfs, spike rows (K=256 +8 pad)
#define CUR_STRIDE 260   // floats, cur rows (256 cols + 4 pad) — injective
#define SMEM_AS    0         // 32*136*2 = 8704 B
#define SMEM_CUR   8704      // 32*260*4 = 33280 B
#define SMEM_SPKA  41984     // 32*264*2 = 16896 B
#define SMEM_SPKB  58880     // 32*264*2 = 16896 B
#define SMEM_TOTAL 75776     // 74 KB -> 2 blocks/CU (148 KB < 160)
// hist/minmax scratch (32 KB) aliases curT only (33.3 KB), dead before L1.

// Per-wave fused GEMM + LIF. C[m][n] = sum_k A[m][k]*(hi + 2^-12 lo)[n][k]
// + bias[n]; depth-1 W prefetch; per-accumulator operand order identical to
// R6..R13 -> bit-exact. After the epilogue the SAME WAVE scans its own cols
// (same-wave LDS dep via lgkmcnt; no block barrier) — waves drift apart and
// cover each other's stalls (the R10/R12 lock-step was the invariant cost).
template<int KCHUNKS, int NT, int ASTRIDE, int FINAL>
__device__ __forceinline__ void gemm_lif_wave(const half_t* __restrict__ Wsw,
                                              const float*  __restrict__ bias,
                                              const half_t* __restrict__ Als,
                                              float*  __restrict__ curT,
                                              half_t* __restrict__ spk_out,
                                              float*  __restrict__ out_final,
                                              int b, int wave, int lane) {
    const int quad = lane >> 4, lr = lane & 15;
    float4v acc_h[2][NT], acc_l[2][NT];
#pragma unroll
    for (int mt = 0; mt < 2; ++mt)
#pragma unroll
        for (int nt = 0; nt < NT; ++nt) {
            acc_h[mt][nt] = (float4v){0.0f, 0.0f, 0.0f, 0.0f};
            acc_l[mt][nt] = (float4v){0.0f, 0.0f, 0.0f, 0.0f};
        }

    half8 wh[NT], wl[NT];
#pragma unroll
    for (int nt = 0; nt < NT; ++nt) {
        const half_t* p = Wsw + ((size_t)(wave * NT + nt) * KCHUNKS) * 1024 + lane * 8;
        wh[nt] = *(const half8*)(p);
        wl[nt] = *(const half8*)(p + 512);
    }
#pragma unroll
    for (int c = 0; c < KCHUNKS; ++c) {
        half8 a[2];
#pragma unroll
        for (int mt = 0; mt < 2; ++mt)
            a[mt] = *(const half8*)(Als + (mt * 16 + lr) * ASTRIDE + c * 32 + quad * 8);
        half8 nwh[NT], nwl[NT];
        if (c + 1 < KCHUNKS) {
#pragma unroll
            for (int nt = 0; nt < NT; ++nt) {
                const half_t* p =
                    Wsw + ((size_t)(wave * NT + nt) * KCHUNKS + c + 1) * 1024 + lane * 8;
                nwh[nt] = *(const half8*)(p);
                nwl[nt] = *(const half8*)(p + 512);
            }
        }
#pragma unroll
        for (int nt = 0; nt < NT; ++nt)
#pragma unroll
            for (int mt = 0; mt < 2; ++mt) {
                acc_h[mt][nt] = __builtin_amdgcn_mfma_f32_16x16x32_f16(a[mt], wh[nt], acc_h[mt][nt], 0, 0, 0);
                acc_l[mt][nt] = __builtin_amdgcn_mfma_f32_16x16x32_f16(a[mt], wl[nt], acc_l[mt][nt], 0, 0, 0);
            }
#pragma unroll
        for (int nt = 0; nt < NT; ++nt) { wh[nt] = nwh[nt]; wl[nt] = nwl[nt]; }
    }

    // epilogue -> curT, own cols only (C/D layout: col=lane&15, row=quad*4+r)
#pragma unroll
    for (int nt = 0; nt < NT; ++nt) {
        int col = (wave * NT + nt) * 16 + lr;
        float bj = bias[col];
#pragma unroll
        for (int mt = 0; mt < 2; ++mt) {
            int rbase = mt * 16 + quad * 4;
#pragma unroll
            for (int r = 0; r < 4; ++r) {
                float v = acc_h[mt][nt][r] + 2.44140625e-04f * acc_l[mt][nt][r];
                curT[(rbase + r) * CUR_STRIDE + col] = v + bj;
            }
        }
    }

    // LIF scan of this wave's own cols — same-wave LDS dependency, no barrier.
    // fp contract OFF (reference mul/add/sub rounding at the threshold).
    if (lane < NT * 16) {
#pragma clang fp contract(off)
        const int col = wave * NT * 16 + lane;
        float mem = 0.0f;
#pragma unroll
        for (int t = 0; t < T_STEPS; ++t) {
            float c = curT[t * CUR_STRIDE + col];
            float reset = (mem - 1.0f > 0.0f) ? 1.0f : 0.0f;
            float p = 0.9f * mem;
            p = p + c;
            mem = p - reset;
            float s = (mem - 1.0f > 0.0f) ? 1.0f : 0.0f;
            if (FINAL) {
                // reference output layout: [t*B + b][h], f32
                out_final[((size_t)t * B_SZ + b) * H3 + col] = s;
            } else {
                spk_out[t * SPK_STRIDE + col] = (half_t)s;
            }
        }
    }
}

// ---------------------------------------------------------------------------
// Mega kernel: one block = one batch b, 512 threads (8 waves), per-wave
// staggered GEMM+scan pipelines, 6 barriers total.
// ---------------------------------------------------------------------------
__global__ __launch_bounds__(512, 4)
void snn_mega_kernel(const float* __restrict__ x,
                     const half_t* __restrict__ ws1, const float* __restrict__ b1,
                     const half_t* __restrict__ ws2, const float* __restrict__ b2,
                     const half_t* __restrict__ ws3, const float* __restrict__ b3,
                     float* __restrict__ out) {
    __shared__ __align__(16) char smem[SMEM_TOTAL];
    half_t* As   = (half_t*)(smem + SMEM_AS);
    float*  curT = (float*) (smem + SMEM_CUR);
    half_t* spkA = (half_t*)(smem + SMEM_SPKA);
    half_t* spkB = (half_t*)(smem + SMEM_SPKB);
    float*  scratch = (float*)(smem + SMEM_CUR);   // pre-L1: minmax + hist

    const int tid  = threadIdx.x;
    const int b    = blockIdx.x;
    const int wave = tid >> 6;
    const int lane = tid & 63;

    // ================= phase 0: latency encode (threads 0..255) ===========
    const int f  = tid & 127;
    const int sh = (tid >> 7) & 1;               // s-half: 0 -> s 0..31, 1 -> 32..63
    const float* xp = x + (size_t)b * (S_SZ * F_INPUT) + (size_t)sh * 32 * F_INPUT + f;

    float v[32];                                 // burst loads, all in flight
    float fmn = 0.0f, fmx = 0.0f;
    if (tid < 256) {
#pragma unroll
        for (int s = 0; s < 32; ++s) {
            float val = xp[(size_t)s * F_INPUT];
            v[s] = (val < 0.75f) ? 0.0f : val;   // gate at ENC_THR
        }
        float mn = 1e30f, mx = -1e30f;
#pragma unroll
        for (int s = 0; s < 32; ++s) {
            mn = fminf(mn, v[s]);
            mx = fmaxf(mx, v[s]);
        }
        scratch[sh * 128 + f]       = mn;
        scratch[256 + sh * 128 + f] = mx;
    }
    __syncthreads();
    if (tid < 256) {
        // exact: min(min half0, min half1) == min(all); same for max
        fmn = fminf(scratch[f], scratch[128 + f]);
        fmx = fmaxf(scratch[256 + f], scratch[384 + f]);
    }
    __syncthreads();

    if (tid < 256) {
        float* hist = scratch;                   // hist[2][32][128] f32 (32 KB)
#pragma unroll
        for (int t = 0; t < T_STEPS; ++t) hist[sh * 4096 + t * 128 + f] = 0.0f;
        // no barrier: each thread touches only its own (sh,*,f) cells
        const float denom = fmx - fmn + 1e-8f;
#pragma unroll
        for (int s = 0; s < 32; ++s) {
            float g  = v[s];
            float xn = (g - fmn) / denom;
            float d  = fmaxf(xn, 0.0100001f);        // clip(xn, LAT_THR+EPS)
            float tt = logf(d / (d - 0.01f));        // log latency code
            tt = tt * 31.0f;
            tt = tt / 11.512935464920229f;           // float32(log((thr+eps)/eps))
            float tr = rintf(tt);                    // half-to-even == jnp.round
            tr = fminf(fmaxf(tr, 0.0f), 31.0f);
            hist[sh * 4096 + (int)tr * 128 + f] += 1.0f;
        }
    }
    __syncthreads();

    // merge halves -> rates (exact k/64) into As (separate region: no barrier
    // needed between hist reads and As writes)
    if (tid < 256) {
#pragma unroll
        for (int i = 0; i < 16; ++i) {
            int idx = tid + i * 256;             // 0..4095
            int t = idx >> 7, ff = idx & 127;
            float cnt = scratch[t * 128 + ff] + scratch[4096 + t * 128 + ff];
            As[t * AS_STRIDE + ff] = (half_t)(cnt * 0.015625f);
        }
    }
    __syncthreads();   // As complete; hist region (curT) now dead

    // ================= layer 1: per-wave GEMM+LIF, K=128, N=256 ===========
    gemm_lif_wave<F_INPUT / 32, 2, AS_STRIDE, 0>(ws1, b1, As, curT, spkA, nullptr,
                                                 b, wave, lane);
    __syncthreads();   // all spkA cols written

    // ================= layer 2: per-wave GEMM+LIF, K=256, N=256 ===========
    gemm_lif_wave<H1 / 32, 2, SPK_STRIDE, 0>(ws2, b2, spkA, curT, spkB, nullptr,
                                             b, wave, lane);
    __syncthreads();   // all spkB cols written

    // ================= layer 3: per-wave GEMM+LIF -> out, K=256, N=128 ====
    gemm_lif_wave<H2 / 32, 1, SPK_STRIDE, 1>(ws3, b3, spkB, curT, nullptr, out,
                                             b, wave, lane);
}

// ---------------------------------------------------------------------------
extern "C" void kernel_launch(void* const* d_in, const int* in_sizes, int n_in,
                              void* d_out, int out_size, void* d_ws, size_t ws_size,
                              hipStream_t stream) {
    const float* x  = (const float*)d_in[0];
    const float* W1 = (const float*)d_in[1];
    const float* b1 = (const float*)d_in[2];
    const float* W2 = (const float*)d_in[3];
    const float* b2 = (const float*)d_in[4];
    const float* W3 = (const float*)d_in[5];
    const float* b3 = (const float*)d_in[6];
    float* out = (float*)d_out;

    char* ws = (char*)d_ws;
    half_t* ws1 = (half_t*)ws;                          // 128 KB (swizzled hi/lo)
    half_t* ws2 = (half_t*)(ws + 128 * 1024);           // 256 KB
    half_t* ws3 = (half_t*)(ws + 384 * 1024);           // 128 KB

    // 0. split + swizzle weights (one dispatch, all layers)
    prep_w_kernel<<<(H1 * F_INPUT + H2 * H1 + H3 * H2) / 256, 256, 0, stream>>>(
        W1, W2, W3, ws1, ws2, ws3);

    // 1. whole network: one block per batch, per-wave staggered pipelines
    snn_mega_kernel<<<B_SZ, 512, 0, stream>>>(x, ws1, b1, ws2, b2, ws3, b3, out);
}